// Round 7
// baseline (66.168 us; speedup 1.0000x reference)
//
#include <hip/hip_runtime.h>

// Problem constants (from reference)
#define BATCH 16
#define NSEG 32
#define HW (512 * 1024)              // 524288 pixels per batch
#define MIN_PIX 50.0f

// Accum kernel: 1-wave blocks, register-resident histogram (no LDS in main
// loop). Per pixel: broadcast-compare against all 32 segs, predicated FMA
// into 128 VGPR accumulators. O(NSEG) VALU but zero latency chains.
#define THREADS 64
#define BPB 128                      // blocks per batch -> 2048 blocks total
#define QUADS 16                     // 4096 px/block / (64 thr * 4 px)

// Accumulator layout in d_ws: acc[b][s][4], comp: 0=cnt 1=su 2=sv 3=s2
#define ACC_FLOATS (BATCH * NSEG * 4)

typedef float f32x2 __attribute__((ext_vector_type(2)));

__global__ __launch_bounds__(THREADS, 2) void ovl_accum(
    const float* __restrict__ flow,   // [B, 2, H, W]
    const int* __restrict__ masks,    // [B, H, W]
    float* __restrict__ acc)          // [B, S, 4], pre-zeroed
{
    __shared__ float red[THREADS][NSEG + 1];   // 8448 B, reduce scratch only

    const int tid = threadIdx.x;
    const int b  = blockIdx.x >> 7;                      // batch
    const int bk = blockIdx.x & (BPB - 1);               // block within batch
    const float* __restrict__ u_base = flow + (size_t)b * 2 * HW;
    const float* __restrict__ v_base = u_base + HW;
    const int*   __restrict__ m_base = masks + (size_t)b * HW;

    f32x2 acc_uv[NSEG];   // (su, sv) per segment
    f32x2 acc_c2[NSEG];   // (cnt, u^2+v^2) per segment
    #pragma unroll
    for (int s = 0; s < NSEG; ++s) {
        acc_uv[s] = (f32x2)(0.0f);
        acc_c2[s] = (f32x2)(0.0f);
    }

#define LOADP(S, Q) { const int p = (((Q) * BPB + bk) * THREADS + tid) * 4; \
        m##S = *(const int4*)(m_base + p);                                  \
        u##S = *(const float4*)(u_base + p);                                \
        v##S = *(const float4*)(v_base + p); }

// One pixel: compare m against every seg (static unroll -> accs stay in
// VGPRs), k in {0,1}, two packed FMAs per segment.
#define PX(mm, uu, vv) {                                                    \
        const float u_ = (uu), v_ = (vv);                                   \
        const int   m_ = (mm) & (NSEG - 1);                                 \
        const float s2_ = fmaf(u_, u_, v_ * v_);                            \
        const f32x2 uv_ = {u_, v_};                                         \
        const f32x2 c2_ = {1.0f, s2_};                                      \
        _Pragma("unroll")                                                   \
        for (int s = 0; s < NSEG; ++s) {                                    \
            const float k = (m_ == s) ? 1.0f : 0.0f;                        \
            const f32x2 k2 = {k, k};                                        \
            acc_uv[s] += k2 * uv_;                                          \
            acc_c2[s] += k2 * c2_;                                          \
        }                                                                   \
    }

#define PROCQ(mq, uq, vq) { PX(mq.x, uq.x, vq.x) PX(mq.y, uq.y, vq.y)       \
                            PX(mq.z, uq.z, vq.z) PX(mq.w, uq.w, vq.w) }

    int4 mA, mB; float4 uA, vA, uB, vB;
    LOADP(A, 0)
    LOADP(B, 1)
    #pragma unroll 1   // keep body ~1.4K insts; don't blow the I-cache
    for (int q = 0; q < QUADS; q += 2) {
        PROCQ(mA, uA, vA)
        if (q + 2 < QUADS) LOADP(A, q + 2)
        PROCQ(mB, uB, vB)
        if (q + 3 < QUADS) LOADP(B, q + 3)
    }

    // Cross-lane reduce via LDS transpose, one component per pass.
    // Write: red[tid][s], bank=(tid+s)%32 -> 2 lanes/bank (free).
    // Read: rotated rows, ~2-way worst case.
#define RPASS(EXPR, CIDX) {                                                 \
        _Pragma("unroll")                                                   \
        for (int s = 0; s < NSEG; ++s) red[tid][s] = (EXPR);                \
        __syncthreads();                                                    \
        const int rs = tid >> 1, rh = tid & 1;                              \
        float sum = 0.0f;                                                   \
        _Pragma("unroll")                                                   \
        for (int i = 0; i < 32; ++i)                                        \
            sum += red[rh * 32 + ((i + tid) & 31)][rs];                     \
        sum += __shfl_xor(sum, 1, 64);                                      \
        if (rh == 0)                                                        \
            unsafeAtomicAdd(&acc[((size_t)b * NSEG + rs) * 4 + (CIDX)], sum);\
        __syncthreads();                                                    \
    }

    RPASS(acc_c2[s].x, 0)   // cnt
    RPASS(acc_uv[s].x, 1)   // su
    RPASS(acc_uv[s].y, 2)   // sv
    RPASS(acc_c2[s].y, 3)   // suu+svv
}

__global__ __launch_bounds__(BATCH * NSEG) void ovl_finalize(
    const float* __restrict__ acc,   // [B*S, 4]
    float* __restrict__ out)         // scalar
{
    const int tid = threadIdx.x;     // 0..511, one per global segment id
    const float cnt = acc[tid * 4 + 0];
    const float su  = acc[tid * 4 + 1];
    const float sv  = acc[tid * 4 + 2];
    const float s2  = acc[tid * 4 + 3];

    const bool is_bg = (tid & (NSEG - 1)) == 0;
    const bool valid = (cnt >= MIN_PIX) && !is_bg;

    const float safe_cnt = fmaxf(cnt, 1.0f);
    const float denom = fmaxf(cnt - 1.0f, 1.0f);
    const float var_sum = (s2 - (su * su + sv * sv) / safe_cnt) / denom;

    float t = valid ? var_sum : 0.0f;
    float n = valid ? 1.0f : 0.0f;

    #pragma unroll
    for (int off = 32; off >= 1; off >>= 1) {
        t += __shfl_down(t, off, 64);
        n += __shfl_down(n, off, 64);
    }

    __shared__ float st[8], sn[8];
    const int wave = tid >> 6;
    const int lane = tid & 63;
    if (lane == 0) { st[wave] = t; sn[wave] = n; }
    __syncthreads();

    if (tid == 0) {
        float tot = 0.0f, ntot = 0.0f;
        #pragma unroll
        for (int w = 0; w < 8; ++w) { tot += st[w]; ntot += sn[w]; }
        out[0] = (ntot > 0.0f) ? (tot / fmaxf(ntot, 1.0f)) : 0.0f;
    }
}

extern "C" void kernel_launch(void* const* d_in, const int* in_sizes, int n_in,
                              void* d_out, int out_size, void* d_ws, size_t ws_size,
                              hipStream_t stream) {
    const float* flow = (const float*)d_in[0];
    const int* masks  = (const int*)d_in[1];
    float* out = (float*)d_out;
    float* acc = (float*)d_ws;

    hipMemsetAsync(acc, 0, ACC_FLOATS * sizeof(float), stream);

    ovl_accum<<<BATCH * BPB, THREADS, 0, stream>>>(flow, masks, acc);
    ovl_finalize<<<1, BATCH * NSEG, 0, stream>>>(acc, out);
}

// Round 8
// 34.890 us; speedup vs baseline: 1.8965x; 1.8965x over previous
//
#include <hip/hip_runtime.h>
#include <hip/hip_fp16.h>

// Problem constants (from reference)
#define BATCH 16
#define NSEG 32
#define HW (512 * 1024)              // 524288 pixels per batch
#define MIN_PIX 50.0f

// Accum kernel: 1-wave blocks, per-thread f16-packed bins in LDS.
// bins[s][tid] = uint2{ half2(su,sv), half2(cnt,s2) } = 8 B/seg/thread
// -> 16 KiB/block -> 10 blocks/CU capacity, entire grid resident.
#define THREADS 64
#define BPB 128                      // blocks per batch -> 2048 blocks total
#define QUADS 16                     // 4096 px/block / (64 thr * 4 px)

// Accumulator layout in d_ws: acc[b][s][4], comp: 0=cnt 1=su 2=sv 3=s2
#define ACC_FLOATS (BATCH * NSEG * 4)

__global__ __launch_bounds__(THREADS) void ovl_accum(
    const float* __restrict__ flow,   // [B, 2, H, W]
    const int* __restrict__ masks,    // [B, H, W]
    float* __restrict__ acc)          // [B, S, 4], pre-zeroed
{
    // Transposed layout: lane footprint = banks (2*tid, 2*tid+1) % 32,
    // independent of s -> deterministic ~4-way on b64, no multinomial spikes.
    __shared__ uint2 bins[NSEG][THREADS];   // 16384 B

    const int tid = threadIdx.x;
    #pragma unroll
    for (int s = 0; s < NSEG; ++s)
        bins[s][tid] = make_uint2(0u, 0u);
    // single wave per block: lockstep, in-order DS pipe

    const int b  = blockIdx.x >> 7;                      // batch
    const int bk = blockIdx.x & (BPB - 1);               // block within batch
    const float* __restrict__ u_base = flow + (size_t)b * 2 * HW;
    const float* __restrict__ v_base = u_base + HW;
    const int*   __restrict__ m_base = masks + (size_t)b * HW;

#define LOADP(S, Q) { const int p = (((Q) * BPB + bk) * THREADS + tid) * 4; \
        m##S = *(const int4*)(m_base + p);                                  \
        u##S = *(const float4*)(u_base + p);                                \
        v##S = *(const float4*)(v_base + p); }

// One pixel: b64 RMW with two packed-f16 adds.
#define PX(mm, uu, vv) {                                                    \
        const int   s  = (mm) & (NSEG - 1);                                 \
        const float u_ = (uu), v_ = (vv);                                   \
        const float s2_ = fmaf(u_, u_, v_ * v_);                            \
        uint2 cur = bins[s][tid];                                           \
        __half2 huv = __hadd2(*(__half2*)&cur.x,                            \
                __halves2half2(__float2half(u_), __float2half(v_)));        \
        __half2 hc2 = __hadd2(*(__half2*)&cur.y,                            \
                __halves2half2(__float2half(1.0f), __float2half(s2_)));     \
        cur.x = *(unsigned int*)&huv;                                       \
        cur.y = *(unsigned int*)&hc2;                                       \
        bins[s][tid] = cur;                                                 \
    }

#define PROCQ(mq, uq, vq) { PX(mq.x, uq.x, vq.x) PX(mq.y, uq.y, vq.y)       \
                            PX(mq.z, uq.z, vq.z) PX(mq.w, uq.w, vq.w) }

    int4 mA, mB; float4 uA, vA, uB, vB;
    LOADP(A, 0)
    LOADP(B, 1)
    #pragma unroll
    for (int q = 0; q < QUADS; q += 2) {
        PROCQ(mA, uA, vA)
        if (q + 2 < QUADS) LOADP(A, q + 2)
        PROCQ(mB, uB, vB)
        if (q + 3 < QUADS) LOADP(B, q + 3)
    }

    __syncthreads();

    // Reduction: 2 lanes per segment (rh selects the packed word), unpack to
    // f32 (exact), sum 64 thread-columns, 2 global fp32 atomics per lane.
    const int rs = tid >> 1, rh = tid & 1;
    const unsigned int* bw = (const unsigned int*)&bins[rs][0];  // [64][2]
    float sx = 0.0f, sy = 0.0f;
    #pragma unroll
    for (int i = 0; i < THREADS; ++i) {
        const int j = (i + rs) & (THREADS - 1);   // rotate to spread banks
        const unsigned int w = bw[j * 2 + rh];
        const float2 f = __half22float2(*(const __half2*)&w);
        sx += f.x; sy += f.y;
    }
    float* dst = &acc[((size_t)b * NSEG + rs) * 4];
    if (rh == 0) {                 // word x = (su, sv)
        unsafeAtomicAdd(dst + 1, sx);
        unsafeAtomicAdd(dst + 2, sy);
    } else {                       // word y = (cnt, s2)
        unsafeAtomicAdd(dst + 0, sx);
        unsafeAtomicAdd(dst + 3, sy);
    }
}

__global__ __launch_bounds__(BATCH * NSEG) void ovl_finalize(
    const float* __restrict__ acc,   // [B*S, 4]
    float* __restrict__ out)         // scalar
{
    const int tid = threadIdx.x;     // 0..511, one per global segment id
    const float cnt = acc[tid * 4 + 0];
    const float su  = acc[tid * 4 + 1];
    const float sv  = acc[tid * 4 + 2];
    const float s2  = acc[tid * 4 + 3];

    const bool is_bg = (tid & (NSEG - 1)) == 0;
    const bool valid = (cnt >= MIN_PIX) && !is_bg;

    const float safe_cnt = fmaxf(cnt, 1.0f);
    const float denom = fmaxf(cnt - 1.0f, 1.0f);
    const float var_sum = (s2 - (su * su + sv * sv) / safe_cnt) / denom;

    float t = valid ? var_sum : 0.0f;
    float n = valid ? 1.0f : 0.0f;

    #pragma unroll
    for (int off = 32; off >= 1; off >>= 1) {
        t += __shfl_down(t, off, 64);
        n += __shfl_down(n, off, 64);
    }

    __shared__ float st[8], sn[8];
    const int wave = tid >> 6;
    const int lane = tid & 63;
    if (lane == 0) { st[wave] = t; sn[wave] = n; }
    __syncthreads();

    if (tid == 0) {
        float tot = 0.0f, ntot = 0.0f;
        #pragma unroll
        for (int w = 0; w < 8; ++w) { tot += st[w]; ntot += sn[w]; }
        out[0] = (ntot > 0.0f) ? (tot / fmaxf(ntot, 1.0f)) : 0.0f;
    }
}

extern "C" void kernel_launch(void* const* d_in, const int* in_sizes, int n_in,
                              void* d_out, int out_size, void* d_ws, size_t ws_size,
                              hipStream_t stream) {
    const float* flow = (const float*)d_in[0];
    const int* masks  = (const int*)d_in[1];
    float* out = (float*)d_out;
    float* acc = (float*)d_ws;

    hipMemsetAsync(acc, 0, ACC_FLOATS * sizeof(float), stream);

    ovl_accum<<<BATCH * BPB, THREADS, 0, stream>>>(flow, masks, acc);
    ovl_finalize<<<1, BATCH * NSEG, 0, stream>>>(acc, out);
}

// Round 9
// 34.230 us; speedup vs baseline: 1.9331x; 1.0193x over previous
//
#include <hip/hip_runtime.h>

// Problem constants (from reference)
#define BATCH 16
#define NSEG 32
#define HW (512 * 1024)              // 524288 pixels per batch
#define MIN_PIX 50.0f

// Accum: 1-wave blocks, per-thread f32x4 bins in LDS, serial RMW (the proven
// R3 champion loop), 4-deep global prefetch, plain-store partials (no atomics,
// no memset kernel).
#define THREADS 64
#define CHUNKS 64                    // blocks per batch -> 1024 blocks total
#define QUADS 32                     // 8192 px/block / (64 thr * 4 px)

// d_ws layout: partials[1024 blocks][128] floats (512 KiB), sc = s*4+c
#define PART_STRIDE 128

__global__ __launch_bounds__(THREADS) void ovl_accum(
    const float* __restrict__ flow,   // [B, 2, H, W]
    const int* __restrict__ masks,    // [B, H, W]
    float* __restrict__ partials)     // [1024][128]
{
    __shared__ float4 bins[THREADS][NSEG];   // 32 KiB

    const int tid = threadIdx.x;
    #pragma unroll
    for (int i = 0; i < NSEG; ++i)
        bins[tid][i] = make_float4(0.0f, 0.0f, 0.0f, 0.0f);
    // single wave per block: lockstep, no barrier needed

    const int bid = blockIdx.x;
    const int b  = bid >> 6;                 // batch
    const int bk = bid & (CHUNKS - 1);       // block within batch
    const float* __restrict__ u_base = flow + (size_t)b * 2 * HW;
    const float* __restrict__ v_base = u_base + HW;
    const int*   __restrict__ m_base = masks + (size_t)b * HW;

#define LOADP(S, Q) { const int p = (((Q) * CHUNKS + bk) * THREADS + tid) * 4; \
        m##S = *(const int4*)(m_base + p);                                     \
        u##S = *(const float4*)(u_base + p);                                   \
        v##S = *(const float4*)(v_base + p); }

// One pixel: minimal serial b128 RMW (R3 structure — fastest measured).
#define PX(mm, uu, vv) {                                                    \
        const int   s  = (mm) & (NSEG - 1);                                 \
        const float u_ = (uu), v_ = (vv);                                   \
        float4 cur = bins[tid][s];                                          \
        cur.x += 1.0f;                                                      \
        cur.y += u_;                                                        \
        cur.z += v_;                                                        \
        cur.w += fmaf(u_, u_, v_ * v_);                                     \
        bins[tid][s] = cur;                                                 \
    }

#define PROCQ(mq, uq, vq) { PX(mq.x, uq.x, vq.x) PX(mq.y, uq.y, vq.y)       \
                            PX(mq.z, uq.z, vq.z) PX(mq.w, uq.w, vq.w) }

    int4 mA, mB, mC, mD; float4 uA, vA, uB, vB, uC, vC, uD, vD;
    LOADP(A, 0)
    LOADP(B, 1)
    LOADP(C, 2)
    LOADP(D, 3)
    #pragma unroll
    for (int q = 0; q < QUADS; q += 4) {
        PROCQ(mA, uA, vA)
        if (q + 4 < QUADS) LOADP(A, q + 4)
        PROCQ(mB, uB, vB)
        if (q + 5 < QUADS) LOADP(B, q + 5)
        PROCQ(mC, uC, vC)
        if (q + 6 < QUADS) LOADP(C, q + 6)
        PROCQ(mD, uD, vD)
        if (q + 7 < QUADS) LOADP(D, q + 7)
    }

    __syncthreads();

    // Reduce the 64 private rows; plain coalesced stores of 128 floats.
    const float* bf = (const float*)bins;    // [64][128] floats
    #pragma unroll
    for (int h = 0; h < 2; ++h) {
        const int pair = tid + h * 64;       // 0..127 = s*4 + c
        float sum = 0.0f;
        #pragma unroll
        for (int j = 0; j < THREADS; ++j)
            sum += bf[j * (NSEG * 4) + pair];
        partials[(size_t)bid * PART_STRIDE + pair] = sum;
    }
}

// One block, 1024 threads: gather 1024x128 partials (coalesced), finalize.
__global__ __launch_bounds__(1024) void ovl_finalize(
    const float* __restrict__ partials,   // [1024][128]
    float* __restrict__ out)              // scalar
{
    __shared__ float sums[BATCH * NSEG * 4];   // 2048 triples, 8 KiB
    const int tid = threadIdx.x;

    // Phase 1: triple T = (b, sc): sum over the 64 blocks of batch b.
    // Consecutive tid -> consecutive sc -> coalesced loads.
    #pragma unroll
    for (int h = 0; h < 2; ++h) {
        const int T = tid + h * 1024;        // 0..2047
        const int b = T >> 7, sc = T & 127;
        float sum = 0.0f;
        #pragma unroll 8
        for (int j = 0; j < CHUNKS; ++j)
            sum += partials[(size_t)(b * CHUNKS + j) * PART_STRIDE + sc];
        sums[T] = sum;
    }
    __syncthreads();

    // Phase 2: 512 threads, one per (b, s).
    float t = 0.0f, n = 0.0f;
    if (tid < BATCH * NSEG) {
        const float cnt = sums[tid * 4 + 0];
        const float su  = sums[tid * 4 + 1];
        const float sv  = sums[tid * 4 + 2];
        const float s2  = sums[tid * 4 + 3];
        const bool is_bg = (tid & (NSEG - 1)) == 0;
        const bool valid = (cnt >= MIN_PIX) && !is_bg;
        const float safe_cnt = fmaxf(cnt, 1.0f);
        const float denom = fmaxf(cnt - 1.0f, 1.0f);
        const float var_sum = (s2 - (su * su + sv * sv) / safe_cnt) / denom;
        t = valid ? var_sum : 0.0f;
        n = valid ? 1.0f : 0.0f;
    }

    #pragma unroll
    for (int off = 32; off >= 1; off >>= 1) {
        t += __shfl_down(t, off, 64);
        n += __shfl_down(n, off, 64);
    }

    __shared__ float st[16], sn[16];
    const int wave = tid >> 6;
    const int lane = tid & 63;
    if (lane == 0) { st[wave] = t; sn[wave] = n; }
    __syncthreads();

    if (tid == 0) {
        float tot = 0.0f, ntot = 0.0f;
        #pragma unroll
        for (int w = 0; w < 8; ++w) { tot += st[w]; ntot += sn[w]; }  // waves 8..15 hold zeros from tid>=512
        out[0] = (ntot > 0.0f) ? (tot / fmaxf(ntot, 1.0f)) : 0.0f;
    }
}

extern "C" void kernel_launch(void* const* d_in, const int* in_sizes, int n_in,
                              void* d_out, int out_size, void* d_ws, size_t ws_size,
                              hipStream_t stream) {
    const float* flow = (const float*)d_in[0];
    const int* masks  = (const int*)d_in[1];
    float* out = (float*)d_out;
    float* partials = (float*)d_ws;

    ovl_accum<<<BATCH * CHUNKS, THREADS, 0, stream>>>(flow, masks, partials);
    ovl_finalize<<<1, 1024, 0, stream>>>(partials, out);
}

// Round 10
// 32.464 us; speedup vs baseline: 2.0382x; 1.0544x over previous
//
#include <hip/hip_runtime.h>
#include <hip/hip_fp16.h>

// Problem constants (from reference)
#define BATCH 16
#define NSEG 32
#define HW (512 * 1024)              // 524288 pixels per batch
#define MIN_PIX 50.0f

// Accum: 1-wave blocks; TWO independent f16-packed bin arrays (chain A/B by
// pixel parity). Separate __shared__ objects -> compiler-provable non-alias
// -> chain A's read only orders behind chain A's write; chain B overlaps.
// 2 x 16 KiB = 32 KiB/block -> 5 blocks/CU, 1024 blocks, 128 px/thread.
#define THREADS 64
#define CHUNKS 64                    // blocks per batch -> 1024 blocks total
#define QUADS 32                     // 8192 px/block / (64 thr * 4 px)

// d_ws layout: partials[1024 blocks][128] floats (512 KiB), idx = s*4+c
#define PART_STRIDE 128

__global__ __launch_bounds__(THREADS) void ovl_accum(
    const float* __restrict__ flow,   // [B, 2, H, W]
    const int* __restrict__ masks,    // [B, H, W]
    float* __restrict__ partials)     // [1024][128]
{
    // Transposed: lane footprint = banks (2*tid)%32, independent of s.
    __shared__ uint2 binsA[NSEG][THREADS];   // 16 KiB
    __shared__ uint2 binsB[NSEG][THREADS];   // 16 KiB

    const int tid = threadIdx.x;
    #pragma unroll
    for (int s = 0; s < NSEG; ++s) {
        binsA[s][tid] = make_uint2(0u, 0u);
        binsB[s][tid] = make_uint2(0u, 0u);
    }
    // single wave per block: lockstep

    const int bid = blockIdx.x;
    const int b  = bid >> 6;                 // batch
    const int bk = bid & (CHUNKS - 1);       // block within batch
    const float* __restrict__ u_base = flow + (size_t)b * 2 * HW;
    const float* __restrict__ v_base = u_base + HW;
    const int*   __restrict__ m_base = masks + (size_t)b * HW;

#define LOADP(S, Q) { const int p = (((Q) * CHUNKS + bk) * THREADS + tid) * 4; \
        m##S = *(const int4*)(m_base + p);                                     \
        u##S = *(const float4*)(u_base + p);                                   \
        v##S = *(const float4*)(v_base + p); }

// One pixel into one chain: b64 RMW with two packed-f16 adds.
#define PXC(BINS, mm, uu, vv) {                                             \
        const int   s  = (mm) & (NSEG - 1);                                 \
        const float u_ = (uu), v_ = (vv);                                   \
        const float s2_ = fmaf(u_, u_, v_ * v_);                            \
        uint2 cur = BINS[s][tid];                                           \
        __half2 huv = __hadd2(*(__half2*)&cur.x,                            \
                __halves2half2(__float2half(u_), __float2half(v_)));        \
        __half2 hc2 = __hadd2(*(__half2*)&cur.y,                            \
                __halves2half2(__float2half(1.0f), __float2half(s2_)));     \
        cur.x = *(unsigned int*)&huv;                                       \
        cur.y = *(unsigned int*)&hc2;                                       \
        BINS[s][tid] = cur;                                                 \
    }

// Quad: alternate chains so consecutive RMWs hit different arrays.
#define PROCQ(mq, uq, vq) { PXC(binsA, mq.x, uq.x, vq.x)                    \
                            PXC(binsB, mq.y, uq.y, vq.y)                    \
                            PXC(binsA, mq.z, uq.z, vq.z)                    \
                            PXC(binsB, mq.w, uq.w, vq.w) }

    int4 mA, mB; float4 uA, vA, uB, vB;
    LOADP(A, 0)
    LOADP(B, 1)
    #pragma unroll
    for (int q = 0; q < QUADS; q += 2) {
        PROCQ(mA, uA, vA)
        if (q + 2 < QUADS) LOADP(A, q + 2)
        PROCQ(mB, uB, vB)
        if (q + 3 < QUADS) LOADP(B, q + 3)
    }

    __syncthreads();

    // Reduce both arrays: 2 lanes per segment (rh picks packed word), unpack
    // to f32 (exact), rotate rows to spread banks, plain coalesced-ish stores.
    const int rs = tid >> 1, rh = tid & 1;
    const unsigned int* wa = (const unsigned int*)&binsA[rs][0];  // [64][2]
    const unsigned int* wb = (const unsigned int*)&binsB[rs][0];
    float sx = 0.0f, sy = 0.0f;
    #pragma unroll
    for (int i = 0; i < THREADS; ++i) {
        const int j = (i + rs) & (THREADS - 1);
        const unsigned int a = wa[j * 2 + rh];
        const unsigned int c = wb[j * 2 + rh];
        const float2 fa = __half22float2(*(const __half2*)&a);
        const float2 fc = __half22float2(*(const __half2*)&c);
        sx += fa.x + fc.x;
        sy += fa.y + fc.y;
    }
    float* dst = &partials[(size_t)bid * PART_STRIDE + rs * 4];
    if (rh == 0) {                 // word x = (su, sv)
        dst[1] = sx;
        dst[2] = sy;
    } else {                       // word y = (cnt, s2)
        dst[0] = sx;
        dst[3] = sy;
    }
}

// One block, 1024 threads: gather 1024x128 partials (coalesced), finalize.
__global__ __launch_bounds__(1024) void ovl_finalize(
    const float* __restrict__ partials,   // [1024][128]
    float* __restrict__ out)              // scalar
{
    __shared__ float sums[BATCH * NSEG * 4];   // 8 KiB
    const int tid = threadIdx.x;

    #pragma unroll
    for (int h = 0; h < 2; ++h) {
        const int T = tid + h * 1024;        // 0..2047
        const int b = T >> 7, sc = T & 127;
        float sum = 0.0f;
        #pragma unroll 8
        for (int j = 0; j < CHUNKS; ++j)
            sum += partials[(size_t)(b * CHUNKS + j) * PART_STRIDE + sc];
        sums[T] = sum;
    }
    __syncthreads();

    float t = 0.0f, n = 0.0f;
    if (tid < BATCH * NSEG) {
        const float cnt = sums[tid * 4 + 0];
        const float su  = sums[tid * 4 + 1];
        const float sv  = sums[tid * 4 + 2];
        const float s2  = sums[tid * 4 + 3];
        const bool is_bg = (tid & (NSEG - 1)) == 0;
        const bool valid = (cnt >= MIN_PIX) && !is_bg;
        const float safe_cnt = fmaxf(cnt, 1.0f);
        const float denom = fmaxf(cnt - 1.0f, 1.0f);
        const float var_sum = (s2 - (su * su + sv * sv) / safe_cnt) / denom;
        t = valid ? var_sum : 0.0f;
        n = valid ? 1.0f : 0.0f;
    }

    #pragma unroll
    for (int off = 32; off >= 1; off >>= 1) {
        t += __shfl_down(t, off, 64);
        n += __shfl_down(n, off, 64);
    }

    __shared__ float st[16], sn[16];
    const int wave = tid >> 6;
    const int lane = tid & 63;
    if (lane == 0) { st[wave] = t; sn[wave] = n; }
    __syncthreads();

    if (tid == 0) {
        float tot = 0.0f, ntot = 0.0f;
        #pragma unroll
        for (int w = 0; w < 8; ++w) { tot += st[w]; ntot += sn[w]; }
        out[0] = (ntot > 0.0f) ? (tot / fmaxf(ntot, 1.0f)) : 0.0f;
    }
}

extern "C" void kernel_launch(void* const* d_in, const int* in_sizes, int n_in,
                              void* d_out, int out_size, void* d_ws, size_t ws_size,
                              hipStream_t stream) {
    const float* flow = (const float*)d_in[0];
    const int* masks  = (const int*)d_in[1];
    float* out = (float*)d_out;
    float* partials = (float*)d_ws;

    ovl_accum<<<BATCH * CHUNKS, THREADS, 0, stream>>>(flow, masks, partials);
    ovl_finalize<<<1, 1024, 0, stream>>>(partials, out);
}